// Round 3
// baseline (216.847 us; speedup 1.0000x reference)
//
#include <hip/hip_runtime.h>
#include <math.h>

#define BSZ  32
#define GSZ  50
#define ATOT 8400
#define NCLS 80
#define CDIM 85
#define TPB  256
#define TPA  512                            // k_assign block: 8 waves, <=1 cand/thread
#define GRIDX ((ATOT + TPB - 1) / TPB)      // 33
#define NPART (GRIDX * BSZ)                 // 1056
#define MAXC 512                            // max or_m candidates per (gt,img); bound ~456

#define EPSF 1e-7f
#define BIGF 100000.0f
#define INFF 1000000000.0f
#define IMGF 640.0f
#define DISF 20.0f        // 2.5 * stride(8)
#define LOGEPS_HI -15.942385f   // logf(2^-23) = ref log(1 - (1-eps)) floor
#define LN2F 0.69314718056f

// fast-math device intrinsics: native v_exp_f32/v_log_f32 (~2 ulp), no OCML wrapper.
__device__ __forceinline__ float fexp(float x){ return __expf(x); }
__device__ __forceinline__ float flog(float x){ return __logf(x); }

__device__ __forceinline__ float sigm(float z){ return 1.0f/(1.0f+fexp(-z)); }
__device__ __forceinline__ float clampp(float s){ return fminf(fmaxf(s, EPSF), 1.f-EPSF); }

// log2-domain log(1-sigmoid(z)): -log2(1+exp(z)), clamped at -23 (= LOGEPS_HI/ln2).
// The *ln2 is applied ONCE after the 80-element sum (saves 1 VALU op/element).
__device__ __forceinline__ float l1ms2(float z){
  return fmaxf(-__log2f(1.f + fexp(z)), -23.0f);
}
__device__ __forceinline__ void acc2(float4& A, float4 w){
  A.x += l1ms2(w.x); A.y += l1ms2(w.y);
  A.z += l1ms2(w.z); A.w += l1ms2(w.w);
}

__device__ __forceinline__ const float* chan_ptr(const float* __restrict__ p8,
                                                 const float* __restrict__ p16,
                                                 const float* __restrict__ p32,
                                                 int b, int a, int ch){
  if (a < 6400) return p8  + ((size_t)(b*CDIM + ch))*6400 + a;
  if (a < 8000) return p16 + ((size_t)(b*CDIM + ch))*1600 + (a-6400);
  return p32 + ((size_t)(b*CDIM + ch))*400 + (a-8000);
}

// cost/iou for one (gt, anchor) pair; clsc via logit identity: log(1-s)-log(s) = -z
__device__ __forceinline__ void compute_pair(
  float cx, float cy, float gw, float gh,
  float px, float py, float pw, float ph,
  float z, float slog,
  float& cost, float& iou, bool& orm, bool& andm, float& clsc)
{
  float hw = gw*0.5f, hh = gh*0.5f;
  bool cm = (px >= fmaxf(cx-DISF,0.f)) && (px <= fminf(cx+DISF,IMGF)) &&
            (py >= fmaxf(cy-DISF,0.f)) && (py <= fminf(cy+DISF,IMGF));
  bool im = (px >= fmaxf(cx-hw,0.f)) && (px <= fminf(cx+hw,IMGF)) &&
            (py >= fmaxf(cy-hh,0.f)) && (py <= fminf(cy+hh,IMGF));
  orm = cm || im;  andm = cm && im;
  float phw = pw*0.5f, phh = ph*0.5f;
  float wx = fmaxf(fminf(cx+hw, px+phw) - fmaxf(cx-hw, px-phw), 0.f);
  float wy = fmaxf(fminf(cy+hh, py+phh) - fmaxf(cy-hh, py-phh), 0.f);
  float inter = wx*wy;
  float uni   = gw*gh + pw*ph - inter;
  iou = inter / fmaxf(uni, 1e-6f);
  clsc = -z - slog;
  cost = clsc + 3.f*(-flog(iou + 1e-8f)) + (andm ? 0.f : BIGF);
}

// ---- K-decode: 4 threads per float4-group (each owns 20 cls channels + 1 box ch).
// Per-wave load pattern: 16 groups x 4 channels -> 4 segments of 256 B.
// [r6/r8 lessons: 8-thread split and streaming+LDS-atomics regressed; keep layout.]
// [R1: full unroll, 4 indep loads/chunk. R2: explicit software pipeline (prefetch
//  next chunk before consuming current), box loads hoisted to the top, log2-domain
//  softplus, per-branch const divisors for i/j.]
// k_prep folded in: threads t < BSZ*GSZ compute class argmax + valid flag;
// global thread 0 zeroes the k_loss completion counter.
__global__ __launch_bounds__(TPB, 4)
void k_decode(const float* __restrict__ p8, const float* __restrict__ p16,
              const float* __restrict__ p32, const float* __restrict__ tgt,
              float* __restrict__ bx, float* __restrict__ by,
              float* __restrict__ bw, float* __restrict__ bh,
              float* __restrict__ obj, float* __restrict__ slog,
              unsigned long long* __restrict__ bits, int* __restrict__ cidx,
              int* __restrict__ vflag, unsigned* __restrict__ done){
  int t = blockIdx.x*blockDim.x + threadIdx.x;   // exactly BSZ*ATOT threads
  int sub = t & 3;
  int g   = t >> 2;                               // float4-group id
  int b = g / (ATOT/4);
  int q = g % (ATOT/4);
  int a0 = q*4;                                   // level edges 6400/8000 are /4
  const float* base; int l; float fs; int aL; int ii, jj;
  if (a0 < 6400){ base = p8;  l = 80; fs = 8.f;  aL = a0;      ii = aL/80; jj = aL - ii*80; }
  else if (a0 < 8000){ base = p16; l = 40; fs = 16.f; aL = a0-6400; ii = aL/40; jj = aL - ii*40; }
  else { base = p32; l = 20; fs = 32.f; aL = a0-8000; ii = aL/20; jj = aL - ii*20; }
  int l2 = l*l;
  int cs = l2 >> 2;                               // channel stride in float4
  const float4* p4 = (const float4*)(base + (size_t)b*CDIM*l2) + (aL >> 2);

  // box-channel loads issued FIRST: latency hides under the class loop.
  // vA = channel 'sub' (4 distinct lines/group); vB = channel 4 (same line for
  // all 4 lanes of a group -> broadcast, no extra HBM traffic).
  float4 vA = p4[(size_t)sub*cs];
  float4 vB = p4[(size_t)4*cs];

  // partial slog over this sub's class channels (5+sub, step 4 -> 20 channels),
  // software-pipelined: 8 loads in flight, 4 independent accumulators.
  const float4* cp = p4 + (size_t)(5+sub)*cs;
  const size_t st4 = (size_t)4*cs;                // step between owned channels
  float4 A0 = make_float4(0.f,0.f,0.f,0.f);
  float4 A1 = A0, A2 = A0, A3 = A0;
  float4 w0 = cp[0], w1 = cp[st4], w2 = cp[2*st4], w3 = cp[3*st4];
  #pragma unroll
  for (int k = 0; k < 20; k += 4){
    float4 n0, n1, n2, n3;
    if (k + 4 < 20){
      n0 = cp[(size_t)(k+4)*st4];
      n1 = cp[(size_t)(k+5)*st4];
      n2 = cp[(size_t)(k+6)*st4];
      n3 = cp[(size_t)(k+7)*st4];
    }
    acc2(A0, w0); acc2(A1, w1); acc2(A2, w2); acc2(A3, w3);
    if (k + 4 < 20){ w0 = n0; w1 = n1; w2 = n2; w3 = n3; }
  }
  float4 S = make_float4(A0.x+A1.x+A2.x+A3.x, A0.y+A1.y+A2.y+A3.y,
                         A0.z+A1.z+A2.z+A3.z, A0.w+A1.w+A2.w+A3.w);
  // reduce across the 4 consecutive lanes of this group (same wave: 4 | 64)
  #pragma unroll
  for (int m = 1; m <= 2; m <<= 1){
    S.x += __shfl_xor(S.x, m, 64);
    S.y += __shfl_xor(S.y, m, 64);
    S.z += __shfl_xor(S.z, m, 64);
    S.w += __shfl_xor(S.w, m, 64);
  }

  float fi = (float)ii;
  uint4 z4 = make_uint4(0u,0u,0u,0u);
  if (sub == 0){
    ((float4*)bx)[g]  = make_float4(((float)(jj  )+sigm(vA.x))*fs, ((float)(jj+1)+sigm(vA.y))*fs,
                                    ((float)(jj+2)+sigm(vA.z))*fs, ((float)(jj+3)+sigm(vA.w))*fs);
    ((float4*)obj)[g] = make_float4(sigm(vB.x), sigm(vB.y), sigm(vB.z), sigm(vB.w));
    ((uint4*)bits)[2*g] = z4;                     // zero 2 of 4 u64 masks
  } else if (sub == 1){
    ((float4*)by)[g]   = make_float4((fi+sigm(vA.x))*fs, (fi+sigm(vA.y))*fs,
                                     (fi+sigm(vA.z))*fs, (fi+sigm(vA.w))*fs);
    ((float4*)slog)[g] = make_float4(S.x*LN2F, S.y*LN2F, S.z*LN2F, S.w*LN2F);
  } else if (sub == 2){
    ((float4*)bw)[g] = make_float4(fexp(vA.x)*fs, fexp(vA.y)*fs, fexp(vA.z)*fs, fexp(vA.w)*fs);
    ((uint4*)bits)[2*g+1] = z4;
  } else {
    ((float4*)bh)[g] = make_float4(fexp(vA.x)*fs, fexp(vA.y)*fs, fexp(vA.z)*fs, fexp(vA.w)*fs);
  }

  // folded k_prep: per-gt one-hot argmax + compact valid flag (coalesced for
  // the fused final reduce); thread 0 zeroes the k_loss completion counter.
  if (t < BSZ*GSZ){
    const float* Tq = tgt + (size_t)t*CDIM;
    int best = 0; float bv = Tq[5];
    for (int c = 1; c < NCLS; c++){
      float vv = Tq[5+c];
      if (vv > bv){ bv = vv; best = c; }
    }
    cidx[t] = best;
    vflag[t] = (Tq[4] == 1.0f) ? 1 : 0;
  }
  if (t == 0) *done = 0u;
}

// monotone float -> sortable-uint map (handles negatives exactly)
__device__ __forceinline__ unsigned f2u(float f){
  unsigned u = __float_as_uint(f);
  return (u & 0x80000000u) ? ~u : (u | 0x80000000u);
}

// ---- K-assign: one block per (gt g, image b).
//  * phase A enumerates only the per-level bounding rects of the or-region
//    (<= ~500 cells of 8400; exact cm/im test unchanged, rect is a superset)
//  * ballot-aggregated compaction: 1 LDS atomic per wave per iter
//  * TPA=512 -> <=1 candidate/thread; top-10 via per-wave bitonic sort on
//    (sortable-cost<<32|idx) u64 keys (deterministic under any compaction order,
//    keys unique) + fused descending-iou sort; 8-way serial merge by thread 0.
__global__ __launch_bounds__(TPA)
void k_assign(const float* __restrict__ p8, const float* __restrict__ p16,
              const float* __restrict__ p32, const float* __restrict__ tgt,
              const int* __restrict__ cidx,
              const float* __restrict__ bx, const float* __restrict__ by,
              const float* __restrict__ bw, const float* __restrict__ bh,
              const float* __restrict__ slog,
              unsigned long long* __restrict__ bits){
  int g = blockIdx.x, b = blockIdx.y;
  const float* T = tgt + ((size_t)b*GSZ + g)*CDIM;
  if (T[4] != 1.0f) return;                 // uniform for whole block
  float cx = T[0], cy = T[1], gw = T[2], gh = T[3];
  float hw = gw*0.5f, hh = gh*0.5f;
  float cL = fmaxf(cx-DISF,0.f), cR = fminf(cx+DISF,IMGF);
  float cT = fmaxf(cy-DISF,0.f), cB = fminf(cy+DISF,IMGF);
  float iL = fmaxf(cx-hw,0.f),  iR = fminf(cx+hw,IMGF);
  float iT = fmaxf(cy-hh,0.f),  iB = fminf(cy+hh,IMGF);
  float gArea = gw*gh;
  int ch = 5 + cidx[b*GSZ + g];
  int t = threadIdx.x;
  int lane = t & 63, wave = t >> 6;

  const float* BX = bx + (size_t)b*ATOT;
  const float* BY = by + (size_t)b*ATOT;
  const float* BW = bw + (size_t)b*ATOT;
  const float* BH = bh + (size_t)b*ATOT;
  const float* SL = slog + (size_t)b*ATOT;

  // union bounding rect of (center | inbox) region (clamps commute with min/max)
  float ux = fmaxf(DISF, hw), uy = fmaxf(DISF, hh);
  float RL = fmaxf(cx-ux, 0.f), RR = fminf(cx+ux, IMGF);
  float RT = fmaxf(cy-uy, 0.f), RB = fminf(cy+uy, IMGF);

  // per-level cell rects, +-1 cell margin (sigmoid offset in (0,1), margin
  // also covers float-floor ulp slop). Explicit scalars: no runtime-indexed
  // arrays (would spill to scratch).
  auto rect = [&](float inv, int l, int& j0r, int& i0r, int& wr, int& hr){
    int a_ = (int)floorf(RL*inv) - 1; if (a_ < 0) a_ = 0;
    int b_ = (int)floorf(RR*inv) + 1; if (b_ > l-1) b_ = l-1;
    int c_ = (int)floorf(RT*inv) - 1; if (c_ < 0) c_ = 0;
    int d_ = (int)floorf(RB*inv) + 1; if (d_ > l-1) d_ = l-1;
    j0r = a_; i0r = c_; wr = b_-a_+1; hr = d_-c_+1;
  };
  int j0_0,i0_0,w_0,h_0, j0_1,i0_1,w_1,h_1, j0_2,i0_2,w_2,h_2;
  rect(0.125f,   80, j0_0,i0_0,w_0,h_0);
  rect(0.0625f,  40, j0_1,i0_1,w_1,h_1);
  rect(0.03125f, 20, j0_2,i0_2,w_2,h_2);
  int o1 = w_0*h_0, o2 = o1 + w_1*h_1, ntot = o2 + w_2*h_2;

  // ---- phase A: rect-bounded mask scan, ballot-compact or_m candidates
  __shared__ int cand[MAXC];
  __shared__ int ncand_sh;
  __shared__ int wand[TPA/64];
  if (t == 0) ncand_sh = 0;
  __syncthreads();

  int myand = 0;                            // lane0 of each wave has full count
  for (int cell = t; cell < ntot; cell += TPA){
    int v = (cell >= o1) + (cell >= o2);
    int loc, jj0, ii0, ww, ll, ab;
    if (v == 0){ loc = cell;    jj0=j0_0; ii0=i0_0; ww=w_0; ll=80; ab=0;    }
    else if (v == 1){ loc = cell-o1; jj0=j0_1; ii0=i0_1; ww=w_1; ll=40; ab=6400; }
    else { loc = cell-o2; jj0=j0_2; ii0=i0_2; ww=w_2; ll=20; ab=8000; }
    int ii = ii0 + loc / ww;
    int jj = jj0 + loc % ww;
    int a  = ab + ii*ll + jj;
    float px = BX[a], py = BY[a];
    bool cm = (px >= cL) && (px <= cR) && (py >= cT) && (py <= cB);
    bool im = (px >= iL) && (px <= iR) && (py >= iT) && (py <= iB);
    bool orm = cm || im, andm = cm && im;
    unsigned long long mo = __ballot(orm);
    myand += __popcll(__ballot(andm));
    if (orm){
      int leader = __ffsll((long long)mo) - 1;
      int base = 0;
      if (lane == leader) base = atomicAdd(&ncand_sh, __popcll(mo));
      base = __shfl(base, leader, 64);
      int pos = base + __popcll(mo & ((1ull << lane) - 1ull));
      if (pos < MAXC) cand[pos] = a | (andm ? 0x10000 : 0);
    }
  }
  if (lane == 0) wand[wave] = myand;        // lane0 runs >= iters of any lane
  __syncthreads();
  int nc = ncand_sh < MAXC ? ncand_sh : MAXC;

  // ---- phase B: <=1 candidate per thread; cost/iou
  unsigned long long ck; float io;
  if (t < nc){
    int packed = cand[t];
    int a = packed & 0xFFFF;
    bool andm = (packed & 0x10000) != 0;
    float px = BX[a], py = BY[a];
    float pw = BW[a], ph = BH[a];
    float phw = pw*0.5f, phh = ph*0.5f;
    float wx = fmaxf(fminf(cx+hw, px+phw) - fmaxf(cx-hw, px-phw), 0.f);
    float wy = fmaxf(fminf(cy+hh, py+phh) - fmaxf(cy-hh, py-phh), 0.f);
    float inter = wx*wy;
    io = inter / fmaxf(gArea + pw*ph - inter, 1e-6f);
    float z = *chan_ptr(p8, p16, p32, b, a, ch);
    float cost = (-z - SL[a]) + 3.f*(-flog(io + 1e-8f)) + (andm ? 0.f : BIGF);
    ck = ((unsigned long long)f2u(cost) << 32) | (unsigned)a;   // (cost,idx) lex key
  } else {
    ck = ~0ull; io = -1.f;
  }

  // per-wave bitonic: ck ascending, io descending (fused, 21 steps)
  __shared__ unsigned long long skey[(TPA/64)*10];
  __shared__ float siou[(TPA/64)*10];
  bool wactive = (wave << 6) < nc;          // wave-uniform
  if (wactive){
    #pragma unroll
    for (int k = 2; k <= 64; k <<= 1){
      #pragma unroll
      for (int j = k >> 1; j > 0; j >>= 1){
        unsigned long long ok = __shfl_xor(ck, j, 64);
        float oi = __shfl_xor(io, j, 64);
        bool tmin = (((lane & k) == 0) == ((lane & j) == 0));
        ck = tmin ? (ck < ok ? ck : ok) : (ck > ok ? ck : ok);
        io = tmin ? fmaxf(io, oi) : fminf(io, oi);
      }
    }
  }
  if (lane < 10){
    skey[wave*10 + lane] = wactive ? ck : ~0ull;
    siou[wave*10 + lane] = wactive ? io : -1.f;
  }
  __syncthreads();

  // ---- serial 8-way merge of sorted top-10 lists (thread 0; ~160 scalar iters)
  if (t == 0){
    int and_cnt = 0;
    #pragma unroll
    for (int q = 0; q < TPA/64; q++) and_cnt += wand[q];
    float k10 = 0.f;
    {
      int h[TPA/64] = {0,0,0,0,0,0,0,0};
      for (int r = 0; r < 10; r++){
        float v = -2.f; int w = -1;
        #pragma unroll
        for (int q = 0; q < TPA/64; q++){
          if (h[q] < 10){
            float vq = siou[q*10 + h[q]];
            if (vq > v){ v = vq; w = q; }
          }
        }
        if (w >= 0) h[w]++;
        k10 += fmaxf(v, 0.f);               // iou*or_m: empties contribute 0
      }
    }
    int dk = (int)k10;
    if (dk < 1) dk = 1;
    int ub = and_cnt > 1 ? and_cnt : 1;
    if (dk > ub) dk = ub;
    int h[TPA/64] = {0,0,0,0,0,0,0,0};
    for (int r = 0; r < dk && r < 10; r++){
      unsigned long long bestk = ~0ull; int w = -1;
      #pragma unroll
      for (int q = 0; q < TPA/64; q++){
        if (h[q] < 10){
          unsigned long long kq = skey[q*10 + h[q]];
          if (kq < bestk){ bestk = kq; w = q; }
        }
      }
      if (bestk == ~0ull) break;            // fewer than dk or_m anchors
      h[w]++;
      int idx = (int)(bestk & 0xFFFFFFFFull);
      atomicOr(&bits[(size_t)b*ATOT + idx], 1ull << g);
    }
  }
}

// ---- K-loss: lazy loads — only fg/overlap anchors (~1%) touch the box arrays.
// k_final fused via threadfence + atomic-counter last-block pattern
// (deterministic: fixed-order reduce done by exactly one block).
__global__ void k_loss(const float* __restrict__ p8, const float* __restrict__ p16,
                       const float* __restrict__ p32, const float* __restrict__ tgt,
                       const int* __restrict__ cidx,
                       const float* __restrict__ bx, const float* __restrict__ by,
                       const float* __restrict__ bw, const float* __restrict__ bh,
                       const float* __restrict__ obj, const float* __restrict__ slog,
                       const unsigned long long* __restrict__ bits,
                       float* __restrict__ partials, const int* __restrict__ vflag,
                       unsigned* __restrict__ done, float* __restrict__ out){
  int b = blockIdx.y;
  int a = blockIdx.x*TPB + threadIdx.x;
  __shared__ float gcx[GSZ], gcy[GSZ], ggw[GSZ], ggh[GSZ], gval[GSZ];
  __shared__ int gci[GSZ];
  for (int k = threadIdx.x; k < GSZ; k += TPB){
    const float* T = tgt + ((size_t)b*GSZ + k)*CDIM;
    gcx[k] = T[0]; gcy[k] = T[1]; ggw[k] = T[2]; ggh[k] = T[3]; gval[k] = T[4];
    gci[k] = cidx[b*GSZ + k];
  }
  __syncthreads();

  float contrib = 0.f;
  if (a < ATOT){
    size_t t = (size_t)b*ATOT + a;
    unsigned long long m = bits[t];
    float o = clampp(obj[t]);
    if (m == 0ull){
      contrib = -flog(1.f - o);                   // background conf BCE only
    } else {
      float px = bx[t], py = by[t], pw = bw[t], ph = bh[t], sl = slog[t];
      if (__builtin_popcountll(m) > 1){
        float bestc = INFF; int bestg = 0;
        for (int g = 0; g < GSZ; g++){
          float c = INFF;
          if (gval[g] == 1.0f){
            float z = *chan_ptr(p8, p16, p32, b, a, 5+gci[g]);
            float iou, clsc; bool orm, andm;
            compute_pair(gcx[g], gcy[g], ggw[g], ggh[g], px, py, pw, ph, z, sl,
                         c, iou, orm, andm, clsc);
          }
          if (c < bestc){ bestc = c; bestg = g; }
        }
        m = 1ull << bestg;
      }
      contrib = -flog(o);                         // foreground conf BCE
      while (m){
        int g = __builtin_ctzll(m);
        m &= m - 1;
        float z = *chan_ptr(p8, p16, p32, b, a, 5+gci[g]);
        float c, iou, clsc; bool orm, andm;
        compute_pair(gcx[g], gcy[g], ggw[g], ggh[g], px, py, pw, ph, z, sl,
                     c, iou, orm, andm, clsc);
        contrib += clsc + 5.f*(1.f - iou*iou);    // l_cls + reg_weight*l_reg
      }
    }
  }

  // wave reduce, then 4 wave-sums via LDS, single global store (NO atomics)
  #pragma unroll
  for (int s2 = 32; s2 > 0; s2 >>= 1) contrib += __shfl_xor(contrib, s2, 64);
  __shared__ float wsum[4];
  if ((threadIdx.x & 63) == 0) wsum[threadIdx.x >> 6] = contrib;
  __syncthreads();
  if (threadIdx.x == 0)
    partials[blockIdx.y*GRIDX + blockIdx.x] = wsum[0]+wsum[1]+wsum[2]+wsum[3];

  // ---- fused k_final: last block to finish reduces all partials
  __shared__ unsigned lastf;
  __threadfence();                                // release partials store
  if (threadIdx.x == 0){
    unsigned old = atomicAdd(done, 1u);
    lastf = (old == (unsigned)(NPART-1)) ? 1u : 0u;
  }
  __syncthreads();
  if (lastf){
    __threadfence();                              // acquire others' partials
    float s = 0.f;
    for (int i = threadIdx.x; i < NPART; i += TPB) s += partials[i];
    int n = 0;
    for (int i = threadIdx.x; i < BSZ*GSZ; i += TPB) n += vflag[i];
    #pragma unroll
    for (int s2 = 32; s2 > 0; s2 >>= 1){
      s += __shfl_xor(s, s2, 64);
      n += __shfl_xor(n, s2, 64);
    }
    __shared__ float fsm[4]; __shared__ int fnm[4];
    if ((threadIdx.x & 63) == 0){ fsm[threadIdx.x >> 6] = s; fnm[threadIdx.x >> 6] = n; }
    __syncthreads();
    if (threadIdx.x == 0){
      float tot = fsm[0]+fsm[1]+fsm[2]+fsm[3];
      int nn = fnm[0]+fnm[1]+fnm[2]+fnm[3];
      if (nn < 1) nn = 1;
      out[0] = tot / (float)nn;
    }
  }
}

extern "C" void kernel_launch(void* const* d_in, const int* in_sizes, int n_in,
                              void* d_out, int out_size, void* d_ws, size_t ws_size,
                              hipStream_t stream) {
  const float* p8  = (const float*)d_in[0];
  const float* p16 = (const float*)d_in[1];
  const float* p32 = (const float*)d_in[2];
  const float* tgt = (const float*)d_in[3];
  float* out = (float*)d_out;

  const size_t BA = (size_t)BSZ*ATOT;
  float* bx   = (float*)d_ws;
  float* by   = bx + BA;
  float* bw   = by + BA;
  float* bh   = bw + BA;
  float* obj  = bh + BA;
  float* slog = obj + BA;
  unsigned long long* bits = (unsigned long long*)(slog + BA);  // 16B-aligned
  int* cidx = (int*)(bits + BA);
  float* partials = (float*)(cidx + BSZ*GSZ);
  int* vflag = (int*)(partials + NPART);
  unsigned* done = (unsigned*)(vflag + BSZ*GSZ);

  dim3 blk(TPB);
  k_decode<<<dim3((unsigned)(BA/TPB)), blk, 0, stream>>>(p8, p16, p32, tgt,
                                                   bx, by, bw, bh, obj, slog, bits,
                                                   cidx, vflag, done);
  k_assign<<<dim3(GSZ, BSZ), dim3(TPA), 0, stream>>>(p8, p16, p32, tgt, cidx,
                                               bx, by, bw, bh, slog, bits);
  k_loss  <<<dim3(GRIDX, BSZ), blk, 0, stream>>>(p8, p16, p32, tgt, cidx,
                                               bx, by, bw, bh, obj, slog, bits,
                                               partials, vflag, done, out);
}

// Round 4
// 151.830 us; speedup vs baseline: 1.4282x; 1.4282x over previous
//
#include <hip/hip_runtime.h>
#include <math.h>

#define BSZ  32
#define GSZ  50
#define ATOT 8400
#define NCLS 80
#define CDIM 85
#define TPB  256
#define TPA  512                            // k_assign block: 8 waves, <=1 cand/thread
#define GRIDX ((ATOT + TPB - 1) / TPB)      // 33
#define NPART (GRIDX * BSZ)                 // 1056
#define MAXC 512                            // max or_m candidates per (gt,img); bound ~456

#define EPSF 1e-7f
#define BIGF 100000.0f
#define INFF 1000000000.0f
#define IMGF 640.0f
#define DISF 20.0f        // 2.5 * stride(8)
#define LOGEPS_HI -15.942385f   // logf(2^-23) = ref log(1 - (1-eps)) floor
#define LN2F 0.69314718056f

// fast-math device intrinsics: native v_exp_f32/v_log_f32 (~2 ulp), no OCML wrapper.
__device__ __forceinline__ float fexp(float x){ return __expf(x); }
__device__ __forceinline__ float flog(float x){ return __logf(x); }

__device__ __forceinline__ float sigm(float z){ return 1.0f/(1.0f+fexp(-z)); }
__device__ __forceinline__ float clampp(float s){ return fminf(fmaxf(s, EPSF), 1.f-EPSF); }

// log2-domain log(1-sigmoid(z)): -log2(1+exp(z)), clamped at -23 (= LOGEPS_HI/ln2).
// The *ln2 is applied ONCE after the 80-element sum (saves 1 VALU op/element).
__device__ __forceinline__ float l1ms2(float z){
  return fmaxf(-__log2f(1.f + fexp(z)), -23.0f);
}
__device__ __forceinline__ void acc2(float4& A, float4 w){
  A.x += l1ms2(w.x); A.y += l1ms2(w.y);
  A.z += l1ms2(w.z); A.w += l1ms2(w.w);
}

__device__ __forceinline__ const float* chan_ptr(const float* __restrict__ p8,
                                                 const float* __restrict__ p16,
                                                 const float* __restrict__ p32,
                                                 int b, int a, int ch){
  if (a < 6400) return p8  + ((size_t)(b*CDIM + ch))*6400 + a;
  if (a < 8000) return p16 + ((size_t)(b*CDIM + ch))*1600 + (a-6400);
  return p32 + ((size_t)(b*CDIM + ch))*400 + (a-8000);
}

// cost/iou for one (gt, anchor) pair; clsc via logit identity: log(1-s)-log(s) = -z
__device__ __forceinline__ void compute_pair(
  float cx, float cy, float gw, float gh,
  float px, float py, float pw, float ph,
  float z, float slog,
  float& cost, float& iou, bool& orm, bool& andm, float& clsc)
{
  float hw = gw*0.5f, hh = gh*0.5f;
  bool cm = (px >= fmaxf(cx-DISF,0.f)) && (px <= fminf(cx+DISF,IMGF)) &&
            (py >= fmaxf(cy-DISF,0.f)) && (py <= fminf(cy+DISF,IMGF));
  bool im = (px >= fmaxf(cx-hw,0.f)) && (px <= fminf(cx+hw,IMGF)) &&
            (py >= fmaxf(cy-hh,0.f)) && (py <= fminf(cy+hh,IMGF));
  orm = cm || im;  andm = cm && im;
  float phw = pw*0.5f, phh = ph*0.5f;
  float wx = fmaxf(fminf(cx+hw, px+phw) - fmaxf(cx-hw, px-phw), 0.f);
  float wy = fmaxf(fminf(cy+hh, py+phh) - fmaxf(cy-hh, py-phh), 0.f);
  float inter = wx*wy;
  float uni   = gw*gh + pw*ph - inter;
  iou = inter / fmaxf(uni, 1e-6f);
  clsc = -z - slog;
  cost = clsc + 3.f*(-flog(iou + 1e-8f)) + (andm ? 0.f : BIGF);
}

// ---- K-decode: 4 threads per float4-group (each owns 20 cls channels + 1 box ch).
// Per-wave load pattern: 16 groups x 4 channels -> 4 segments of 256 B.
// [r6/r8 lessons: 8-thread split and streaming+LDS-atomics regressed; keep layout.]
// [R1: full unroll, 4 indep loads/chunk. R2: explicit software pipeline, box loads
//  hoisted, log2-domain softplus, const divisors. R3: fused-final REVERTED —
//  __threadfence() last-block pattern cost 80 µs of pure stall (cross-XCD L2
//  writeback serialization); separate launches are cheaper on MI355X.]
// k_prep folded in: threads t < BSZ*GSZ compute class argmax + valid flag.
__global__ __launch_bounds__(TPB, 4)
void k_decode(const float* __restrict__ p8, const float* __restrict__ p16,
              const float* __restrict__ p32, const float* __restrict__ tgt,
              float* __restrict__ bx, float* __restrict__ by,
              float* __restrict__ bw, float* __restrict__ bh,
              float* __restrict__ obj, float* __restrict__ slog,
              unsigned long long* __restrict__ bits, int* __restrict__ cidx,
              int* __restrict__ vflag){
  int t = blockIdx.x*blockDim.x + threadIdx.x;   // exactly BSZ*ATOT threads
  int sub = t & 3;
  int g   = t >> 2;                               // float4-group id
  int b = g / (ATOT/4);
  int q = g % (ATOT/4);
  int a0 = q*4;                                   // level edges 6400/8000 are /4
  const float* base; int l; float fs; int aL; int ii, jj;
  if (a0 < 6400){ base = p8;  l = 80; fs = 8.f;  aL = a0;      ii = aL/80; jj = aL - ii*80; }
  else if (a0 < 8000){ base = p16; l = 40; fs = 16.f; aL = a0-6400; ii = aL/40; jj = aL - ii*40; }
  else { base = p32; l = 20; fs = 32.f; aL = a0-8000; ii = aL/20; jj = aL - ii*20; }
  int l2 = l*l;
  int cs = l2 >> 2;                               // channel stride in float4
  const float4* p4 = (const float4*)(base + (size_t)b*CDIM*l2) + (aL >> 2);

  // box-channel loads issued FIRST: latency hides under the class loop.
  float4 vA = p4[(size_t)sub*cs];
  float4 vB = p4[(size_t)4*cs];

  // partial slog over this sub's class channels (5+sub, step 4 -> 20 channels),
  // software-pipelined: 8 loads in flight, 4 independent accumulators.
  const float4* cp = p4 + (size_t)(5+sub)*cs;
  const size_t st4 = (size_t)4*cs;                // step between owned channels
  float4 A0 = make_float4(0.f,0.f,0.f,0.f);
  float4 A1 = A0, A2 = A0, A3 = A0;
  float4 w0 = cp[0], w1 = cp[st4], w2 = cp[2*st4], w3 = cp[3*st4];
  #pragma unroll
  for (int k = 0; k < 20; k += 4){
    float4 n0, n1, n2, n3;
    if (k + 4 < 20){
      n0 = cp[(size_t)(k+4)*st4];
      n1 = cp[(size_t)(k+5)*st4];
      n2 = cp[(size_t)(k+6)*st4];
      n3 = cp[(size_t)(k+7)*st4];
    }
    acc2(A0, w0); acc2(A1, w1); acc2(A2, w2); acc2(A3, w3);
    if (k + 4 < 20){ w0 = n0; w1 = n1; w2 = n2; w3 = n3; }
  }
  float4 S = make_float4(A0.x+A1.x+A2.x+A3.x, A0.y+A1.y+A2.y+A3.y,
                         A0.z+A1.z+A2.z+A3.z, A0.w+A1.w+A2.w+A3.w);
  // reduce across the 4 consecutive lanes of this group (same wave: 4 | 64)
  #pragma unroll
  for (int m = 1; m <= 2; m <<= 1){
    S.x += __shfl_xor(S.x, m, 64);
    S.y += __shfl_xor(S.y, m, 64);
    S.z += __shfl_xor(S.z, m, 64);
    S.w += __shfl_xor(S.w, m, 64);
  }

  float fi = (float)ii;
  uint4 z4 = make_uint4(0u,0u,0u,0u);
  if (sub == 0){
    ((float4*)bx)[g]  = make_float4(((float)(jj  )+sigm(vA.x))*fs, ((float)(jj+1)+sigm(vA.y))*fs,
                                    ((float)(jj+2)+sigm(vA.z))*fs, ((float)(jj+3)+sigm(vA.w))*fs);
    ((float4*)obj)[g] = make_float4(sigm(vB.x), sigm(vB.y), sigm(vB.z), sigm(vB.w));
    ((uint4*)bits)[2*g] = z4;                     // zero 2 of 4 u64 masks
  } else if (sub == 1){
    ((float4*)by)[g]   = make_float4((fi+sigm(vA.x))*fs, (fi+sigm(vA.y))*fs,
                                     (fi+sigm(vA.z))*fs, (fi+sigm(vA.w))*fs);
    ((float4*)slog)[g] = make_float4(S.x*LN2F, S.y*LN2F, S.z*LN2F, S.w*LN2F);
  } else if (sub == 2){
    ((float4*)bw)[g] = make_float4(fexp(vA.x)*fs, fexp(vA.y)*fs, fexp(vA.z)*fs, fexp(vA.w)*fs);
    ((uint4*)bits)[2*g+1] = z4;
  } else {
    ((float4*)bh)[g] = make_float4(fexp(vA.x)*fs, fexp(vA.y)*fs, fexp(vA.z)*fs, fexp(vA.w)*fs);
  }

  // folded k_prep: per-gt one-hot argmax + compact valid flag (coalesced for
  // k_final's reduce — replaces 544 KB of strided tgt reads with 6.4 KB).
  if (t < BSZ*GSZ){
    const float* Tq = tgt + (size_t)t*CDIM;
    int best = 0; float bv = Tq[5];
    for (int c = 1; c < NCLS; c++){
      float vv = Tq[5+c];
      if (vv > bv){ bv = vv; best = c; }
    }
    cidx[t] = best;
    vflag[t] = (Tq[4] == 1.0f) ? 1 : 0;
  }
}

// monotone float -> sortable-uint map (handles negatives exactly)
__device__ __forceinline__ unsigned f2u(float f){
  unsigned u = __float_as_uint(f);
  return (u & 0x80000000u) ? ~u : (u | 0x80000000u);
}

// ---- K-assign: one block per (gt g, image b).
//  * phase A enumerates only the per-level bounding rects of the or-region
//    (<= ~500 cells of 8400; exact cm/im test unchanged, rect is a superset)
//  * ballot-aggregated compaction: 1 LDS atomic per wave per iter
//  * TPA=512 -> <=1 candidate/thread; top-10 via per-wave bitonic sort on
//    (sortable-cost<<32|idx) u64 keys (deterministic under any compaction order,
//    keys unique) + fused descending-iou sort; 8-way serial merge by thread 0.
__global__ __launch_bounds__(TPA)
void k_assign(const float* __restrict__ p8, const float* __restrict__ p16,
              const float* __restrict__ p32, const float* __restrict__ tgt,
              const int* __restrict__ cidx,
              const float* __restrict__ bx, const float* __restrict__ by,
              const float* __restrict__ bw, const float* __restrict__ bh,
              const float* __restrict__ slog,
              unsigned long long* __restrict__ bits){
  int g = blockIdx.x, b = blockIdx.y;
  const float* T = tgt + ((size_t)b*GSZ + g)*CDIM;
  if (T[4] != 1.0f) return;                 // uniform for whole block
  float cx = T[0], cy = T[1], gw = T[2], gh = T[3];
  float hw = gw*0.5f, hh = gh*0.5f;
  float cL = fmaxf(cx-DISF,0.f), cR = fminf(cx+DISF,IMGF);
  float cT = fmaxf(cy-DISF,0.f), cB = fminf(cy+DISF,IMGF);
  float iL = fmaxf(cx-hw,0.f),  iR = fminf(cx+hw,IMGF);
  float iT = fmaxf(cy-hh,0.f),  iB = fminf(cy+hh,IMGF);
  float gArea = gw*gh;
  int ch = 5 + cidx[b*GSZ + g];
  int t = threadIdx.x;
  int lane = t & 63, wave = t >> 6;

  const float* BX = bx + (size_t)b*ATOT;
  const float* BY = by + (size_t)b*ATOT;
  const float* BW = bw + (size_t)b*ATOT;
  const float* BH = bh + (size_t)b*ATOT;
  const float* SL = slog + (size_t)b*ATOT;

  // union bounding rect of (center | inbox) region (clamps commute with min/max)
  float ux = fmaxf(DISF, hw), uy = fmaxf(DISF, hh);
  float RL = fmaxf(cx-ux, 0.f), RR = fminf(cx+ux, IMGF);
  float RT = fmaxf(cy-uy, 0.f), RB = fminf(cy+uy, IMGF);

  // per-level cell rects, +-1 cell margin (sigmoid offset in (0,1), margin
  // also covers float-floor ulp slop). Explicit scalars: no runtime-indexed
  // arrays (would spill to scratch).
  auto rect = [&](float inv, int l, int& j0r, int& i0r, int& wr, int& hr){
    int a_ = (int)floorf(RL*inv) - 1; if (a_ < 0) a_ = 0;
    int b_ = (int)floorf(RR*inv) + 1; if (b_ > l-1) b_ = l-1;
    int c_ = (int)floorf(RT*inv) - 1; if (c_ < 0) c_ = 0;
    int d_ = (int)floorf(RB*inv) + 1; if (d_ > l-1) d_ = l-1;
    j0r = a_; i0r = c_; wr = b_-a_+1; hr = d_-c_+1;
  };
  int j0_0,i0_0,w_0,h_0, j0_1,i0_1,w_1,h_1, j0_2,i0_2,w_2,h_2;
  rect(0.125f,   80, j0_0,i0_0,w_0,h_0);
  rect(0.0625f,  40, j0_1,i0_1,w_1,h_1);
  rect(0.03125f, 20, j0_2,i0_2,w_2,h_2);
  int o1 = w_0*h_0, o2 = o1 + w_1*h_1, ntot = o2 + w_2*h_2;

  // ---- phase A: rect-bounded mask scan, ballot-compact or_m candidates
  __shared__ int cand[MAXC];
  __shared__ int ncand_sh;
  __shared__ int wand[TPA/64];
  if (t == 0) ncand_sh = 0;
  __syncthreads();

  int myand = 0;                            // lane0 of each wave has full count
  for (int cell = t; cell < ntot; cell += TPA){
    int v = (cell >= o1) + (cell >= o2);
    int loc, jj0, ii0, ww, ll, ab;
    if (v == 0){ loc = cell;    jj0=j0_0; ii0=i0_0; ww=w_0; ll=80; ab=0;    }
    else if (v == 1){ loc = cell-o1; jj0=j0_1; ii0=i0_1; ww=w_1; ll=40; ab=6400; }
    else { loc = cell-o2; jj0=j0_2; ii0=i0_2; ww=w_2; ll=20; ab=8000; }
    int ii = ii0 + loc / ww;
    int jj = jj0 + loc % ww;
    int a  = ab + ii*ll + jj;
    float px = BX[a], py = BY[a];
    bool cm = (px >= cL) && (px <= cR) && (py >= cT) && (py <= cB);
    bool im = (px >= iL) && (px <= iR) && (py >= iT) && (py <= iB);
    bool orm = cm || im, andm = cm && im;
    unsigned long long mo = __ballot(orm);
    myand += __popcll(__ballot(andm));
    if (orm){
      int leader = __ffsll((long long)mo) - 1;
      int base = 0;
      if (lane == leader) base = atomicAdd(&ncand_sh, __popcll(mo));
      base = __shfl(base, leader, 64);
      int pos = base + __popcll(mo & ((1ull << lane) - 1ull));
      if (pos < MAXC) cand[pos] = a | (andm ? 0x10000 : 0);
    }
  }
  if (lane == 0) wand[wave] = myand;        // lane0 runs >= iters of any lane
  __syncthreads();
  int nc = ncand_sh < MAXC ? ncand_sh : MAXC;

  // ---- phase B: <=1 candidate per thread; cost/iou
  unsigned long long ck; float io;
  if (t < nc){
    int packed = cand[t];
    int a = packed & 0xFFFF;
    bool andm = (packed & 0x10000) != 0;
    float px = BX[a], py = BY[a];
    float pw = BW[a], ph = BH[a];
    float phw = pw*0.5f, phh = ph*0.5f;
    float wx = fmaxf(fminf(cx+hw, px+phw) - fmaxf(cx-hw, px-phw), 0.f);
    float wy = fmaxf(fminf(cy+hh, py+phh) - fmaxf(cy-hh, py-phh), 0.f);
    float inter = wx*wy;
    io = inter / fmaxf(gArea + pw*ph - inter, 1e-6f);
    float z = *chan_ptr(p8, p16, p32, b, a, ch);
    float cost = (-z - SL[a]) + 3.f*(-flog(io + 1e-8f)) + (andm ? 0.f : BIGF);
    ck = ((unsigned long long)f2u(cost) << 32) | (unsigned)a;   // (cost,idx) lex key
  } else {
    ck = ~0ull; io = -1.f;
  }

  // per-wave bitonic: ck ascending, io descending (fused, 21 steps)
  __shared__ unsigned long long skey[(TPA/64)*10];
  __shared__ float siou[(TPA/64)*10];
  bool wactive = (wave << 6) < nc;          // wave-uniform
  if (wactive){
    #pragma unroll
    for (int k = 2; k <= 64; k <<= 1){
      #pragma unroll
      for (int j = k >> 1; j > 0; j >>= 1){
        unsigned long long ok = __shfl_xor(ck, j, 64);
        float oi = __shfl_xor(io, j, 64);
        bool tmin = (((lane & k) == 0) == ((lane & j) == 0));
        ck = tmin ? (ck < ok ? ck : ok) : (ck > ok ? ck : ok);
        io = tmin ? fmaxf(io, oi) : fminf(io, oi);
      }
    }
  }
  if (lane < 10){
    skey[wave*10 + lane] = wactive ? ck : ~0ull;
    siou[wave*10 + lane] = wactive ? io : -1.f;
  }
  __syncthreads();

  // ---- serial 8-way merge of sorted top-10 lists (thread 0; ~160 scalar iters)
  if (t == 0){
    int and_cnt = 0;
    #pragma unroll
    for (int q = 0; q < TPA/64; q++) and_cnt += wand[q];
    float k10 = 0.f;
    {
      int h[TPA/64] = {0,0,0,0,0,0,0,0};
      for (int r = 0; r < 10; r++){
        float v = -2.f; int w = -1;
        #pragma unroll
        for (int q = 0; q < TPA/64; q++){
          if (h[q] < 10){
            float vq = siou[q*10 + h[q]];
            if (vq > v){ v = vq; w = q; }
          }
        }
        if (w >= 0) h[w]++;
        k10 += fmaxf(v, 0.f);               // iou*or_m: empties contribute 0
      }
    }
    int dk = (int)k10;
    if (dk < 1) dk = 1;
    int ub = and_cnt > 1 ? and_cnt : 1;
    if (dk > ub) dk = ub;
    int h[TPA/64] = {0,0,0,0,0,0,0,0};
    for (int r = 0; r < dk && r < 10; r++){
      unsigned long long bestk = ~0ull; int w = -1;
      #pragma unroll
      for (int q = 0; q < TPA/64; q++){
        if (h[q] < 10){
          unsigned long long kq = skey[q*10 + h[q]];
          if (kq < bestk){ bestk = kq; w = q; }
        }
      }
      if (bestk == ~0ull) break;            // fewer than dk or_m anchors
      h[w]++;
      int idx = (int)(bestk & 0xFFFFFFFFull);
      atomicOr(&bits[(size_t)b*ATOT + idx], 1ull << g);
    }
  }
}

// ---- K-loss: lazy loads — only fg/overlap anchors (~1%) touch the box arrays
__global__ void k_loss(const float* __restrict__ p8, const float* __restrict__ p16,
                       const float* __restrict__ p32, const float* __restrict__ tgt,
                       const int* __restrict__ cidx,
                       const float* __restrict__ bx, const float* __restrict__ by,
                       const float* __restrict__ bw, const float* __restrict__ bh,
                       const float* __restrict__ obj, const float* __restrict__ slog,
                       const unsigned long long* __restrict__ bits,
                       float* __restrict__ partials){
  int b = blockIdx.y;
  int a = blockIdx.x*TPB + threadIdx.x;
  __shared__ float gcx[GSZ], gcy[GSZ], ggw[GSZ], ggh[GSZ], gval[GSZ];
  __shared__ int gci[GSZ];
  for (int k = threadIdx.x; k < GSZ; k += TPB){
    const float* T = tgt + ((size_t)b*GSZ + k)*CDIM;
    gcx[k] = T[0]; gcy[k] = T[1]; ggw[k] = T[2]; ggh[k] = T[3]; gval[k] = T[4];
    gci[k] = cidx[b*GSZ + k];
  }
  __syncthreads();

  float contrib = 0.f;
  if (a < ATOT){
    size_t t = (size_t)b*ATOT + a;
    unsigned long long m = bits[t];
    float o = clampp(obj[t]);
    if (m == 0ull){
      contrib = -flog(1.f - o);                   // background conf BCE only
    } else {
      float px = bx[t], py = by[t], pw = bw[t], ph = bh[t], sl = slog[t];
      if (__builtin_popcountll(m) > 1){
        float bestc = INFF; int bestg = 0;
        for (int g = 0; g < GSZ; g++){
          float c = INFF;
          if (gval[g] == 1.0f){
            float z = *chan_ptr(p8, p16, p32, b, a, 5+gci[g]);
            float iou, clsc; bool orm, andm;
            compute_pair(gcx[g], gcy[g], ggw[g], ggh[g], px, py, pw, ph, z, sl,
                         c, iou, orm, andm, clsc);
          }
          if (c < bestc){ bestc = c; bestg = g; }
        }
        m = 1ull << bestg;
      }
      contrib = -flog(o);                         // foreground conf BCE
      while (m){
        int g = __builtin_ctzll(m);
        m &= m - 1;
        float z = *chan_ptr(p8, p16, p32, b, a, 5+gci[g]);
        float c, iou, clsc; bool orm, andm;
        compute_pair(gcx[g], gcy[g], ggw[g], ggh[g], px, py, pw, ph, z, sl,
                     c, iou, orm, andm, clsc);
        contrib += clsc + 5.f*(1.f - iou*iou);    // l_cls + reg_weight*l_reg
      }
    }
  }

  // wave reduce, then 4 wave-sums via LDS, single global store (NO atomics)
  #pragma unroll
  for (int s2 = 32; s2 > 0; s2 >>= 1) contrib += __shfl_xor(contrib, s2, 64);
  __shared__ float wsum[4];
  if ((threadIdx.x & 63) == 0) wsum[threadIdx.x >> 6] = contrib;
  __syncthreads();
  if (threadIdx.x == 0)
    partials[blockIdx.y*GRIDX + blockIdx.x] = wsum[0]+wsum[1]+wsum[2]+wsum[3];
}

// ---- K-final: reduce 1056 partials + count valid gts (compact vflag) + divide
__global__ void k_final(const float* __restrict__ partials,
                        const int* __restrict__ vflag, float* __restrict__ out){
  int t = threadIdx.x;
  float s = 0.f;
  for (int i = t; i < NPART; i += TPB) s += partials[i];
  int n = 0;
  for (int i = t; i < BSZ*GSZ; i += TPB) n += vflag[i];
  #pragma unroll
  for (int s2 = 32; s2 > 0; s2 >>= 1){
    s += __shfl_xor(s, s2, 64);
    n += __shfl_xor(n, s2, 64);
  }
  __shared__ float sh[4]; __shared__ int shn[4];
  if ((t & 63) == 0){ sh[t >> 6] = s; shn[t >> 6] = n; }
  __syncthreads();
  if (t == 0){
    float tot = sh[0]+sh[1]+sh[2]+sh[3];
    int nn = shn[0]+shn[1]+shn[2]+shn[3];
    if (nn < 1) nn = 1;
    out[0] = tot / (float)nn;
  }
}

extern "C" void kernel_launch(void* const* d_in, const int* in_sizes, int n_in,
                              void* d_out, int out_size, void* d_ws, size_t ws_size,
                              hipStream_t stream) {
  const float* p8  = (const float*)d_in[0];
  const float* p16 = (const float*)d_in[1];
  const float* p32 = (const float*)d_in[2];
  const float* tgt = (const float*)d_in[3];
  float* out = (float*)d_out;

  const size_t BA = (size_t)BSZ*ATOT;
  float* bx   = (float*)d_ws;
  float* by   = bx + BA;
  float* bw   = by + BA;
  float* bh   = bw + BA;
  float* obj  = bh + BA;
  float* slog = obj + BA;
  unsigned long long* bits = (unsigned long long*)(slog + BA);  // 16B-aligned
  int* cidx = (int*)(bits + BA);
  float* partials = (float*)(cidx + BSZ*GSZ);
  int* vflag = (int*)(partials + NPART);

  dim3 blk(TPB);
  k_decode<<<dim3((unsigned)(BA/TPB)), blk, 0, stream>>>(p8, p16, p32, tgt,
                                                   bx, by, bw, bh, obj, slog, bits,
                                                   cidx, vflag);
  k_assign<<<dim3(GSZ, BSZ), dim3(TPA), 0, stream>>>(p8, p16, p32, tgt, cidx,
                                               bx, by, bw, bh, slog, bits);
  k_loss  <<<dim3(GRIDX, BSZ), blk, 0, stream>>>(p8, p16, p32, tgt, cidx,
                                               bx, by, bw, bh, obj, slog, bits, partials);
  k_final <<<1, blk, 0, stream>>>(partials, vflag, out);
}